// Round 18
// baseline (226.171 us; speedup 1.0000x reference)
//
#include <hip/hip_runtime.h>

typedef unsigned short u16;
typedef unsigned int u32;
typedef __attribute__((ext_vector_type(2))) unsigned int u32x2;
typedef __attribute__((ext_vector_type(4))) unsigned int u32x4;
typedef __attribute__((ext_vector_type(8))) short short8;
typedef __attribute__((ext_vector_type(8))) _Float16 half8;
typedef __attribute__((ext_vector_type(2))) __fp16 fp16x2;
typedef __attribute__((ext_vector_type(4))) float floatx4;

__device__ __forceinline__ u16 f2h(float f){ _Float16 h = (_Float16)f; return __builtin_bit_cast(u16, h); }
__device__ __forceinline__ u32 pkrtz(float a, float b){
  fp16x2 h = __builtin_amdgcn_cvt_pkrtz(a, b);
  return __builtin_bit_cast(u32, h);
}
__device__ __forceinline__ u32 pkmax0(u32 a){
  u32 d, z = 0;
  asm("v_pk_max_f16 %0, %1, %2" : "=v"(d) : "v"(a), "v"(z));
  return d;
}
__device__ __forceinline__ u32 pkadd(u32 a, u32 b){
  u32 d;
  asm("v_pk_add_f16 %0, %1, %2" : "=v"(d) : "v"(a), "v"(b));
  return d;
}
__device__ __forceinline__ u32 pkmul(u32 a, u32 b){
  u32 d;
  asm("v_pk_mul_f16 %0, %1, %2" : "=v"(d) : "v"(a), "v"(b));
  return d;
}
__device__ __forceinline__ u32 pkfma(u32 a, u32 b, u32 c){
  u32 d;
  asm("v_pk_fma_f16 %0, %1, %2, %3" : "=v"(d) : "v"(a), "v"(b), "v"(c));
  return d;
}

struct PlanePtrs { const void* p[9]; };
struct PrepArgs {
  const float* src[9]; u16* dst[9]; int blk0[10]; int HW[9];
  const float* l0_w; const float* res_w; const float* l1_w;
  u16* l0T; u16* resT; u16* l1T;
  int ptrans_blocks;
};

// ---------------- prep: 9 plane transposes + weight conversions, ONE launch
// 16-style fragment order: of = ft*16 + (lane&15), k = ks*32 + (lane>>4)*8 + e
__device__ __forceinline__ void wconv_one(const float* src, u16* dst, int fin, int fout, int t){
  int per = fin * fout;
  int m = t / per, r = t - m*per;
  int KS = fin >> 5;
  int e = r & 7;
  int lane = (r >> 3) & 63;
  int fs = r >> 9;
  int ks = fs % KS, ft = fs / KS;
  int of = ft*16 + (lane & 15);
  int k  = ks*32 + (lane >> 4)*8 + e;
  dst[t] = f2h(src[(size_t)m*per + (size_t)k*fout + of]);
}

__global__ void prep_all_kernel(PrepArgs a){
  __shared__ float tile[32][257];
  int bi = blockIdx.x;
  if (bi < a.ptrans_blocks){
    int i = 0;
    #pragma unroll
    for (int k = 1; k < 9; k++) if (bi >= a.blk0[k]) i = k;
    const float* src = a.src[i];
    u16* dst = a.dst[i];
    const int HW = a.HW[i];
    const int t = threadIdx.x;
    const size_t hw0 = (size_t)(bi - a.blk0[i]) * 256;
    #pragma unroll
    for (int c = 0; c < 32; c++) tile[c][t] = src[(size_t)c*HW + hw0 + t];
    __syncthreads();
    u32* d32 = (u32*)(dst + hw0*32);
    #pragma unroll
    for (int k = 0; k < 16; k++){
      int idx = k*512 + t*2;
      int j = idx >> 5, cc = idx & 31;
      u32 lo = f2h(tile[cc][j]);
      u32 hi = f2h(tile[cc+1][j]);
      d32[k*256 + t] = lo | (hi << 16);
    }
  } else {
    int t = (bi - a.ptrans_blocks)*256 + threadIdx.x;
    if (t < 24576){ wconv_one(a.l0_w, a.l0T, 96, 256, t); return; }
    t -= 24576;
    if (t < 589824){ wconv_one(a.res_w, a.resT, 256, 256, t); return; }
    t -= 589824;
    if (t < 4096){ wconv_one(a.l1_w, a.l1T, 256, 16, t); }
  }
}

// ---------------- standalone interp fallback (untransposed planes -> feats)
__global__ void interp_fb_kernel(const float* __restrict__ pts, const float* __restrict__ aabb,
                                 PlanePtrs pp, u16* __restrict__ feats, int N)
{
  int n = blockIdx.x*256 + threadIdx.x;
  if (n >= N) return;
  float xn[3];
  #pragma unroll
  for (int d=0; d<3; d++){
    float lo = aabb[d], hi = aabb[3+d];
    xn[d] = (pts[(size_t)n*3 + d] - lo) * (2.0f/(hi - lo)) - 1.0f;
  }
  const int c0s[3] = {0,0,1};
  const int c1s[3] = {1,2,2};
  #pragma unroll
  for (int s=0; s<3; s++){
    const int R = 128 << s;
    float prod[32];
    #pragma unroll
    for (int p=0; p<3; p++){
      float fx = (xn[c0s[p]] + 1.0f) * 0.5f * (float)(R-1);
      float fy = (xn[c1s[p]] + 1.0f) * 0.5f * (float)(R-1);
      float fx0 = fminf(fmaxf(floorf(fx), 0.0f), (float)(R-2));
      float fy0 = fminf(fmaxf(floorf(fy), 0.0f), (float)(R-2));
      int x0 = (int)fx0, y0 = (int)fy0;
      float wx = fx - fx0, wy = fy - fy0;
      float w00 = (1.0f-wx)*(1.0f-wy), w01 = wx*(1.0f-wy);
      float w10 = (1.0f-wx)*wy,        w11 = wx*wy;
      const size_t HW = (size_t)R*R;
      const float* b00f = (const float*)pp.p[s*3+p] + (size_t)y0*R + x0;
      #pragma unroll 4
      for (int c=0; c<32; c++){
        const float* q = b00f + (size_t)c*HW;
        float val = q[0]*w00 + q[1]*w01 + q[R]*w10 + q[R+1]*w11;
        prod[c] = (p == 0) ? val : prod[c]*val;
      }
    }
    #pragma unroll
    for (int vv=0; vv<4; vv++){
      short8 pk8;
      #pragma unroll
      for (int e=0; e<8; e++) pk8[e] = (short)f2h(prod[vv*8+e]);
      *(short8*)(feats + (size_t)n*96 + s*32 + vv*8) = pk8;
    }
  }
}

// ---------------- fused gather + MLP (fp16 MFMA, A=weights B=activations^T)
// X (single 32KB): [64 pts][256 feat] f16, byte = (pt*512 + feat*2) ^ ((pt&31)<<4).
// R14 configuration (verified best). R18 delta: gather work assignment is
// (pt = tid&63, v = tid>>6) so each half-wave's LDS writes hit slots
// ((s*4+v)^pt) for pt=0..31 = all 32 banks once -> conflict-free (old
// (tid>>2, tid&3) mapping had pt 0..15 -> 4-way, the residual 5.4e6).
template<int KSTEPS>
__device__ __forceinline__ void mm_tile(const u16* X, const u16* __restrict__ WTs,
                                        int ftbase, int lane, floatx4 acc[4][4])
{
  const int lr = lane & 15, lg = lane >> 4;
  #pragma unroll 1
  for (int ks=0; ks<KSTEPS; ks++){
    half8 x[4];
    #pragma unroll
    for (int cf=0; cf<4; cf++){
      int pt = cf*16 + lr;
      int byt = (pt*512 + (ks*32 + lg*8)*2) ^ ((pt & 31) << 4);
      x[cf] = *(const half8*)((const char*)X + byt);
    }
    half8 w[4];
    #pragma unroll
    for (int rf=0; rf<4; rf++)
      w[rf] = *(const half8*)(WTs + ((size_t)((ftbase+rf)*KSTEPS + ks)*64 + lane)*8);
    __builtin_amdgcn_s_setprio(1);
    #pragma unroll
    for (int rf=0; rf<4; rf++)
      #pragma unroll
      for (int cf=0; cf<4; cf++)
        acc[rf][cf] = __builtin_amdgcn_mfma_f32_16x16x32_f16(w[rf], x[cf], acc[rf][cf], 0, 0, 0);
    __builtin_amdgcn_s_setprio(0);
  }
}

__device__ __forceinline__ void init_acc(const float* b, int wb, int lg, floatx4 acc[4][4]){
  #pragma unroll
  for (int rf=0; rf<4; rf++){
    float4 v = *(const float4*)(b + wb + rf*16 + lg*4);
    floatx4 bi = (floatx4){v.x, v.y, v.z, v.w};
    #pragma unroll
    for (int cf=0; cf<4; cf++) acc[rf][cf] = bi;
  }
}

template<int MODE>   // 0 = feats from buffer, 1 = fused gather
__global__ __launch_bounds__(256, 3) void mlp_kernel(
    const float* __restrict__ pts, const float* __restrict__ aabb, PlanePtrs pp,
    const u16* __restrict__ feats,
    const u16* __restrict__ l0T, const u16* __restrict__ resT, const u16* __restrict__ l1T,
    const float* __restrict__ l0_b, const float* __restrict__ res_b, const float* __restrict__ l1_b,
    float* __restrict__ out)
{
  __shared__ u16 X[64*256];
  const int tid = threadIdx.x;
  const int wave = tid >> 6, lane = tid & 63;
  const int lr = lane & 15, lg = lane >> 4;
  const int n0 = blockIdx.x * 64;
  const int ftbase = wave * 4;
  const int wb = wave * 64;

  if constexpr (MODE == 1){
    // ---- fused interp, packed-f16 blend: wave v handles channels v*8..v*8+7
    //      of ALL 64 points (pt = lane). Conflict-free LDS writes.
    const int pt = tid & 63, v = tid >> 6;
    const int n = n0 + pt;
    float xn[3];
    #pragma unroll
    for (int d=0; d<3; d++){
      float lo = aabb[d], hi = aabb[3+d];
      xn[d] = (pts[(size_t)n*3 + d] - lo) * (2.0f/(hi - lo)) - 1.0f;
    }
    const int c0s[3] = {0,0,1};
    const int c1s[3] = {1,2,2};
    #pragma unroll
    for (int s=0; s<3; s++){
      const int R = 128 << s;
      u32x4 prod;
      #pragma unroll
      for (int p=0; p<3; p++){
        float fx = (xn[c0s[p]] + 1.0f) * 0.5f * (float)(R-1);
        float fy = (xn[c1s[p]] + 1.0f) * 0.5f * (float)(R-1);
        float fx0 = fminf(fmaxf(floorf(fx), 0.0f), (float)(R-2));
        float fy0 = fminf(fmaxf(floorf(fy), 0.0f), (float)(R-2));
        int x0 = (int)fx0, y0 = (int)fy0;
        float wx = fx - fx0, wy = fy - fy0;
        u32 w00p = pkrtz((1.0f-wx)*(1.0f-wy), (1.0f-wx)*(1.0f-wy));
        u32 w01p = pkrtz(wx*(1.0f-wy),        wx*(1.0f-wy));
        u32 w10p = pkrtz((1.0f-wx)*wy,        (1.0f-wx)*wy);
        u32 w11p = pkrtz(wx*wy,               wx*wy);
        const u16* base = (const u16*)pp.p[s*3 + p];
        const u16* b00 = base + ((size_t)y0*R + x0)*32 + v*8;
        const u16* b10 = b00 + (size_t)R*32;
        u32x4 h00 = *(const u32x4*)b00;
        u32x4 h01 = *(const u32x4*)(b00 + 32);
        u32x4 h10 = *(const u32x4*)b10;
        u32x4 h11 = *(const u32x4*)(b10 + 32);
        #pragma unroll
        for (int i=0; i<4; i++){
          u32 a = pkmul(h00[i], w00p);
          a = pkfma(h01[i], w01p, a);
          a = pkfma(h10[i], w10p, a);
          a = pkfma(h11[i], w11p, a);
          prod[i] = (p == 0) ? a : pkmul(prod[i], a);
        }
      }
      int byt = (pt*512 + (s*32 + v*8)*2) ^ ((pt & 31) << 4);
      *(u32x4*)((char*)X + byt) = prod;
    }
  } else {
    #pragma unroll
    for (int i=0; i<3; i++){
      int id = tid + i*256;
      int row = id / 12, sub = id - row*12;
      short8 v = *(const short8*)(feats + (size_t)(n0+row)*96 + sub*8);
      int byt = (row*512 + sub*16) ^ ((row & 31) << 4);
      *(short8*)((char*)X + byt) = v;
    }
  }
  __syncthreads();

  floatx4 acc[4][4];
  u32 pk[4][4][2];

  // ---- L0: K=96
  init_acc(l0_b, wb, lg, acc);
  mm_tile<3>(X, l0T, ftbase, lane, acc);
  __syncthreads();
  #pragma unroll
  for (int rf=0; rf<4; rf++){
    int fby = (wb + rf*16 + lg*4)*2;
    #pragma unroll
    for (int cf=0; cf<4; cf++){
      int pt = cf*16 + lr;
      u32 p0 = pkrtz(acc[rf][cf][0], acc[rf][cf][1]);
      u32 p1 = pkrtz(acc[rf][cf][2], acc[rf][cf][3]);
      pk[rf][cf][0] = p0; pk[rf][cf][1] = p1;
      int byt = (pt*512 + fby) ^ ((pt & 31) << 4);
      *(u32x2*)((char*)X + byt) = (u32x2){p0, p1};
    }
  }
  __syncthreads();

  // ---- 3 ResBlocks
  for (int rb=0; rb<3; rb++){
    const u16* W0 = resT + (size_t)(rb*3+0)*65536;
    const u16* W1 = resT + (size_t)(rb*3+1)*65536;
    const u16* W2 = resT + (size_t)(rb*3+2)*65536;
    const float* b0 = res_b + (rb*3+0)*256;
    const float* b1 = res_b + (rb*3+1)*256;
    const float* b2 = res_b + (rb*3+2)*256;

    init_acc(b0, wb, lg, acc);
    mm_tile<8>(X, W0, ftbase, lane, acc);
    __syncthreads();
    #pragma unroll
    for (int rf=0; rf<4; rf++){
      int fby = (wb + rf*16 + lg*4)*2;
      #pragma unroll
      for (int cf=0; cf<4; cf++){
        int pt = cf*16 + lr;
        u32 p0 = pkadd(pk[rf][cf][0], pkmax0(pkrtz(acc[rf][cf][0], acc[rf][cf][1])));
        u32 p1 = pkadd(pk[rf][cf][1], pkmax0(pkrtz(acc[rf][cf][2], acc[rf][cf][3])));
        pk[rf][cf][0] = p0; pk[rf][cf][1] = p1;   // pk now holds res
        int byt = (pt*512 + fby) ^ ((pt & 31) << 4);
        *(u32x2*)((char*)X + byt) = (u32x2){p0, p1};
      }
    }
    __syncthreads();

    init_acc(b1, wb, lg, acc);
    mm_tile<8>(X, W1, ftbase, lane, acc);
    __syncthreads();
    #pragma unroll
    for (int rf=0; rf<4; rf++){
      int fby = (wb + rf*16 + lg*4)*2;
      #pragma unroll
      for (int cf=0; cf<4; cf++){
        int pt = cf*16 + lr;
        u32 p0 = pkmax0(pkrtz(acc[rf][cf][0], acc[rf][cf][1]));
        u32 p1 = pkmax0(pkrtz(acc[rf][cf][2], acc[rf][cf][3]));
        int byt = (pt*512 + fby) ^ ((pt & 31) << 4);
        *(u32x2*)((char*)X + byt) = (u32x2){p0, p1};
      }
    }
    __syncthreads();

    init_acc(b2, wb, lg, acc);
    mm_tile<8>(X, W2, ftbase, lane, acc);
    __syncthreads();
    #pragma unroll
    for (int rf=0; rf<4; rf++){
      int fby = (wb + rf*16 + lg*4)*2;
      #pragma unroll
      for (int cf=0; cf<4; cf++){
        int pt = cf*16 + lr;
        u32 p0 = pkadd(pkmax0(pkrtz(acc[rf][cf][0], acc[rf][cf][1])), pk[rf][cf][0]);
        u32 p1 = pkadd(pkmax0(pkrtz(acc[rf][cf][2], acc[rf][cf][3])), pk[rf][cf][1]);
        pk[rf][cf][0] = p0; pk[rf][cf][1] = p1;   // pk now holds new x
        int byt = (pt*512 + fby) ^ ((pt & 31) << 4);
        *(u32x2*)((char*)X + byt) = (u32x2){p0, p1};
      }
    }
    __syncthreads();
  }

  // ---- final: 256 -> 16, sigmoid
  floatx4 accf;
  {
    float4 bo = *(const float4*)(l1_b + lg*4);
    accf = (floatx4){bo.x, bo.y, bo.z, bo.w};
  }
  #pragma unroll 1
  for (int ks=0; ks<8; ks++){
    int pt = wave*16 + lr;
    int byt = (pt*512 + (ks*32 + lg*8)*2) ^ ((pt&31)<<4);
    half8 x = *(const half8*)((const char*)X + byt);
    half8 w = *(const half8*)(l1T + ((size_t)ks*64 + lane)*8);
    accf = __builtin_amdgcn_mfma_f32_16x16x32_f16(w, x, accf, 0, 0, 0);
  }
  {
    int n_out = n0 + wave*16 + lr;
    float4 o;
    o.x = 1.0f / (1.0f + __expf(-accf[0]));
    o.y = 1.0f / (1.0f + __expf(-accf[1]));
    o.z = 1.0f / (1.0f + __expf(-accf[2]));
    o.w = 1.0f / (1.0f + __expf(-accf[3]));
    *(float4*)(out + (size_t)n_out*16 + lg*4) = o;
  }
}

// ---------------- host ----------------
extern "C" void kernel_launch(void* const* d_in, const int* in_sizes, int n_in,
                              void* d_out, int out_size, void* d_ws, size_t ws_size,
                              hipStream_t stream)
{
  const float* pts  = (const float*)d_in[0];
  const float* aabb = (const float*)d_in[1];
  const float* l0_w = (const float*)d_in[11];
  const float* res_w= (const float*)d_in[13];
  const float* l1_w = (const float*)d_in[15];
  const float* l0_b = (const float*)d_in[12];
  const float* res_b= (const float*)d_in[14];
  const float* l1_b = (const float*)d_in[16];
  const int N = in_sizes[0] / 3;

  char* ws = (char*)d_ws;
  const size_t woff_l0  = 0;                          // 256*96*2
  const size_t woff_res = 49152;                      // 9*65536*2
  const size_t woff_l1  = woff_res + 9*65536*2;       // 16*256*2
  const size_t foff     = woff_l1 + 8192;             // fallback feats: N*96*2
  const size_t poff     = foff + (size_t)N*96*2;      // f16 planes

  static const int HWs[3] = {128*128, 256*256, 512*512};
  size_t pel[9]; size_t tot = 0;
  for (int s=0;s<3;s++) for (int p=0;p<3;p++){ pel[s*3+p] = tot; tot += (size_t)HWs[s]*32; }

  const bool tr_mode = (ws_size >= poff + tot*2);

  PlanePtrs pp;
  if (tr_mode){
    u16* pbase = (u16*)(ws + poff);
    PrepArgs pa;
    int b0 = 0;
    for (int i=0;i<9;i++){
      int s = i/3;
      pa.src[i] = (const float*)d_in[2+i];
      pa.dst[i] = pbase + pel[i];
      pa.blk0[i] = b0;
      pa.HW[i] = HWs[s];
      b0 += HWs[s]/256;
      pp.p[i] = pbase + pel[i];
    }
    pa.blk0[9] = b0;
    pa.ptrans_blocks = b0;
    pa.l0_w = l0_w; pa.res_w = res_w; pa.l1_w = l1_w;
    pa.l0T = (u16*)(ws+woff_l0); pa.resT = (u16*)(ws+woff_res); pa.l1T = (u16*)(ws+woff_l1);
    const int wconv_blocks = (24576+589824+4096+255)/256;
    prep_all_kernel<<<b0 + wconv_blocks, 256, 0, stream>>>(pa);

    mlp_kernel<1><<<N/64, 256, 0, stream>>>(pts, aabb, pp, (const u16*)nullptr,
        (const u16*)(ws+woff_l0), (const u16*)(ws+woff_res), (const u16*)(ws+woff_l1),
        l0_b, res_b, l1_b, (float*)d_out);
  } else {
    PrepArgs pa;
    for (int i=0;i<9;i++){ pa.src[i] = nullptr; pa.dst[i] = nullptr; pa.blk0[i] = 0; pa.HW[i] = HWs[i/3]; pp.p[i] = d_in[2+i]; }
    pa.blk0[9] = 0;
    pa.ptrans_blocks = 0;
    pa.l0_w = l0_w; pa.res_w = res_w; pa.l1_w = l1_w;
    pa.l0T = (u16*)(ws+woff_l0); pa.resT = (u16*)(ws+woff_res); pa.l1T = (u16*)(ws+woff_l1);
    const int wconv_blocks = (24576+589824+4096+255)/256;
    prep_all_kernel<<<wconv_blocks, 256, 0, stream>>>(pa);

    interp_fb_kernel<<<(N+255)/256, 256, 0, stream>>>(pts, aabb, pp, (u16*)(ws+foff), N);
    mlp_kernel<0><<<N/64, 256, 0, stream>>>(pts, aabb, pp, (const u16*)(ws+foff),
        (const u16*)(ws+woff_l0), (const u16*)(ws+woff_res), (const u16*)(ws+woff_l1),
        l0_b, res_b, l1_b, (float*)d_out);
  }
}

// Round 19
// 221.054 us; speedup vs baseline: 1.0231x; 1.0231x over previous
//
#include <hip/hip_runtime.h>

typedef unsigned short u16;
typedef unsigned int u32;
typedef __attribute__((ext_vector_type(2))) unsigned int u32x2;
typedef __attribute__((ext_vector_type(4))) unsigned int u32x4;
typedef __attribute__((ext_vector_type(8))) short short8;
typedef __attribute__((ext_vector_type(8))) _Float16 half8;
typedef __attribute__((ext_vector_type(2))) __fp16 fp16x2;
typedef __attribute__((ext_vector_type(4))) float floatx4;

__device__ __forceinline__ u16 f2h(float f){ _Float16 h = (_Float16)f; return __builtin_bit_cast(u16, h); }
__device__ __forceinline__ u32 pkrtz(float a, float b){
  fp16x2 h = __builtin_amdgcn_cvt_pkrtz(a, b);
  return __builtin_bit_cast(u32, h);
}
__device__ __forceinline__ u32 pkmax0(u32 a){
  u32 d, z = 0;
  asm("v_pk_max_f16 %0, %1, %2" : "=v"(d) : "v"(a), "v"(z));
  return d;
}
__device__ __forceinline__ u32 pkadd(u32 a, u32 b){
  u32 d;
  asm("v_pk_add_f16 %0, %1, %2" : "=v"(d) : "v"(a), "v"(b));
  return d;
}
__device__ __forceinline__ u32 pkmul(u32 a, u32 b){
  u32 d;
  asm("v_pk_mul_f16 %0, %1, %2" : "=v"(d) : "v"(a), "v"(b));
  return d;
}
__device__ __forceinline__ u32 pkfma(u32 a, u32 b, u32 c){
  u32 d;
  asm("v_pk_fma_f16 %0, %1, %2, %3" : "=v"(d) : "v"(a), "v"(b), "v"(c));
  return d;
}

struct PlanePtrs { const void* p[9]; };
struct PrepArgs {
  const float* src[9]; u16* dst[9]; int blk0[10]; int HW[9];
  const float* l0_w; const float* res_w; const float* l1_w;
  u16* l0T; u16* resT; u16* l1T;
  int ptrans_blocks;
};

// ---------------- prep: 9 plane transposes + weight conversions, ONE launch
// 16-style fragment order: of = ft*16 + (lane&15), k = ks*32 + (lane>>4)*8 + e
__device__ __forceinline__ void wconv_one(const float* src, u16* dst, int fin, int fout, int t){
  int per = fin * fout;
  int m = t / per, r = t - m*per;
  int KS = fin >> 5;
  int e = r & 7;
  int lane = (r >> 3) & 63;
  int fs = r >> 9;
  int ks = fs % KS, ft = fs / KS;
  int of = ft*16 + (lane & 15);
  int k  = ks*32 + (lane >> 4)*8 + e;
  dst[t] = f2h(src[(size_t)m*per + (size_t)k*fout + of]);
}

__global__ void prep_all_kernel(PrepArgs a){
  __shared__ float tile[32][257];
  int bi = blockIdx.x;
  if (bi < a.ptrans_blocks){
    int i = 0;
    #pragma unroll
    for (int k = 1; k < 9; k++) if (bi >= a.blk0[k]) i = k;
    const float* src = a.src[i];
    u16* dst = a.dst[i];
    const int HW = a.HW[i];
    const int t = threadIdx.x;
    const size_t hw0 = (size_t)(bi - a.blk0[i]) * 256;
    #pragma unroll
    for (int c = 0; c < 32; c++) tile[c][t] = src[(size_t)c*HW + hw0 + t];
    __syncthreads();
    u32* d32 = (u32*)(dst + hw0*32);
    #pragma unroll
    for (int k = 0; k < 16; k++){
      int idx = k*512 + t*2;
      int j = idx >> 5, cc = idx & 31;
      u32 lo = f2h(tile[cc][j]);
      u32 hi = f2h(tile[cc+1][j]);
      d32[k*256 + t] = lo | (hi << 16);
    }
  } else {
    int t = (bi - a.ptrans_blocks)*256 + threadIdx.x;
    if (t < 24576){ wconv_one(a.l0_w, a.l0T, 96, 256, t); return; }
    t -= 24576;
    if (t < 589824){ wconv_one(a.res_w, a.resT, 256, 256, t); return; }
    t -= 589824;
    if (t < 4096){ wconv_one(a.l1_w, a.l1T, 256, 16, t); }
  }
}

// ---------------- standalone interp fallback (untransposed planes -> feats)
__global__ void interp_fb_kernel(const float* __restrict__ pts, const float* __restrict__ aabb,
                                 PlanePtrs pp, u16* __restrict__ feats, int N)
{
  int n = blockIdx.x*256 + threadIdx.x;
  if (n >= N) return;
  float xn[3];
  #pragma unroll
  for (int d=0; d<3; d++){
    float lo = aabb[d], hi = aabb[3+d];
    xn[d] = (pts[(size_t)n*3 + d] - lo) * (2.0f/(hi - lo)) - 1.0f;
  }
  const int c0s[3] = {0,0,1};
  const int c1s[3] = {1,2,2};
  #pragma unroll
  for (int s=0; s<3; s++){
    const int R = 128 << s;
    float prod[32];
    #pragma unroll
    for (int p=0; p<3; p++){
      float fx = (xn[c0s[p]] + 1.0f) * 0.5f * (float)(R-1);
      float fy = (xn[c1s[p]] + 1.0f) * 0.5f * (float)(R-1);
      float fx0 = fminf(fmaxf(floorf(fx), 0.0f), (float)(R-2));
      float fy0 = fminf(fmaxf(floorf(fy), 0.0f), (float)(R-2));
      int x0 = (int)fx0, y0 = (int)fy0;
      float wx = fx - fx0, wy = fy - fy0;
      float w00 = (1.0f-wx)*(1.0f-wy), w01 = wx*(1.0f-wy);
      float w10 = (1.0f-wx)*wy,        w11 = wx*wy;
      const size_t HW = (size_t)R*R;
      const float* b00f = (const float*)pp.p[s*3+p] + (size_t)y0*R + x0;
      #pragma unroll 4
      for (int c=0; c<32; c++){
        const float* q = b00f + (size_t)c*HW;
        float val = q[0]*w00 + q[1]*w01 + q[R]*w10 + q[R+1]*w11;
        prod[c] = (p == 0) ? val : prod[c]*val;
      }
    }
    #pragma unroll
    for (int vv=0; vv<4; vv++){
      short8 pk8;
      #pragma unroll
      for (int e=0; e<8; e++) pk8[e] = (short)f2h(prod[vv*8+e]);
      *(short8*)(feats + (size_t)n*96 + s*32 + vv*8) = pk8;
    }
  }
}

// ---------------- fused gather + MLP (fp16 MFMA, A=weights B=activations^T)
// X (single 32KB): [64 pts][256 feat] f16, byte = (pt*512 + feat*2) ^ ((pt&31)<<4).
// R17 configuration (verified best 221 us): 16x16x32 MFMA, ks loop NOT
// unrolled, NO prefetch, gather mapping (pt=tid>>2, v=tid&3) for coalesced
// 32B-run plane reads. Ledger: dbuf(R9), sort(R11/12), prefetch(R13-spill),
// 32x32(R15/16), gather remap(R18) all regressed vs this.
template<int KSTEPS>
__device__ __forceinline__ void mm_tile(const u16* X, const u16* __restrict__ WTs,
                                        int ftbase, int lane, floatx4 acc[4][4])
{
  const int lr = lane & 15, lg = lane >> 4;
  #pragma unroll 1
  for (int ks=0; ks<KSTEPS; ks++){
    half8 x[4];
    #pragma unroll
    for (int cf=0; cf<4; cf++){
      int pt = cf*16 + lr;
      int byt = (pt*512 + (ks*32 + lg*8)*2) ^ ((pt & 31) << 4);
      x[cf] = *(const half8*)((const char*)X + byt);
    }
    half8 w[4];
    #pragma unroll
    for (int rf=0; rf<4; rf++)
      w[rf] = *(const half8*)(WTs + ((size_t)((ftbase+rf)*KSTEPS + ks)*64 + lane)*8);
    __builtin_amdgcn_s_setprio(1);
    #pragma unroll
    for (int rf=0; rf<4; rf++)
      #pragma unroll
      for (int cf=0; cf<4; cf++)
        acc[rf][cf] = __builtin_amdgcn_mfma_f32_16x16x32_f16(w[rf], x[cf], acc[rf][cf], 0, 0, 0);
    __builtin_amdgcn_s_setprio(0);
  }
}

__device__ __forceinline__ void init_acc(const float* b, int wb, int lg, floatx4 acc[4][4]){
  #pragma unroll
  for (int rf=0; rf<4; rf++){
    float4 v = *(const float4*)(b + wb + rf*16 + lg*4);
    floatx4 bi = (floatx4){v.x, v.y, v.z, v.w};
    #pragma unroll
    for (int cf=0; cf<4; cf++) acc[rf][cf] = bi;
  }
}

template<int MODE>   // 0 = feats from buffer, 1 = fused gather
__global__ __launch_bounds__(256, 3) void mlp_kernel(
    const float* __restrict__ pts, const float* __restrict__ aabb, PlanePtrs pp,
    const u16* __restrict__ feats,
    const u16* __restrict__ l0T, const u16* __restrict__ resT, const u16* __restrict__ l1T,
    const float* __restrict__ l0_b, const float* __restrict__ res_b, const float* __restrict__ l1_b,
    float* __restrict__ out)
{
  __shared__ u16 X[64*256];
  const int tid = threadIdx.x;
  const int wave = tid >> 6, lane = tid & 63;
  const int lr = lane & 15, lg = lane >> 4;
  const int n0 = blockIdx.x * 64;
  const int ftbase = wave * 4;
  const int wb = wave * 64;

  if constexpr (MODE == 1){
    // ---- fused interp, packed-f16 blend: 4 threads/point, 8 channels each
    const int pt = tid >> 2, v = tid & 3;
    const int n = n0 + pt;
    float xn[3];
    #pragma unroll
    for (int d=0; d<3; d++){
      float lo = aabb[d], hi = aabb[3+d];
      xn[d] = (pts[(size_t)n*3 + d] - lo) * (2.0f/(hi - lo)) - 1.0f;
    }
    const int c0s[3] = {0,0,1};
    const int c1s[3] = {1,2,2};
    #pragma unroll
    for (int s=0; s<3; s++){
      const int R = 128 << s;
      u32x4 prod;
      #pragma unroll
      for (int p=0; p<3; p++){
        float fx = (xn[c0s[p]] + 1.0f) * 0.5f * (float)(R-1);
        float fy = (xn[c1s[p]] + 1.0f) * 0.5f * (float)(R-1);
        float fx0 = fminf(fmaxf(floorf(fx), 0.0f), (float)(R-2));
        float fy0 = fminf(fmaxf(floorf(fy), 0.0f), (float)(R-2));
        int x0 = (int)fx0, y0 = (int)fy0;
        float wx = fx - fx0, wy = fy - fy0;
        u32 w00p = pkrtz((1.0f-wx)*(1.0f-wy), (1.0f-wx)*(1.0f-wy));
        u32 w01p = pkrtz(wx*(1.0f-wy),        wx*(1.0f-wy));
        u32 w10p = pkrtz((1.0f-wx)*wy,        (1.0f-wx)*wy);
        u32 w11p = pkrtz(wx*wy,               wx*wy);
        const u16* base = (const u16*)pp.p[s*3 + p];
        const u16* b00 = base + ((size_t)y0*R + x0)*32 + v*8;
        const u16* b10 = b00 + (size_t)R*32;
        u32x4 h00 = *(const u32x4*)b00;
        u32x4 h01 = *(const u32x4*)(b00 + 32);
        u32x4 h10 = *(const u32x4*)b10;
        u32x4 h11 = *(const u32x4*)(b10 + 32);
        #pragma unroll
        for (int i=0; i<4; i++){
          u32 a = pkmul(h00[i], w00p);
          a = pkfma(h01[i], w01p, a);
          a = pkfma(h10[i], w10p, a);
          a = pkfma(h11[i], w11p, a);
          prod[i] = (p == 0) ? a : pkmul(prod[i], a);
        }
      }
      int byt = (pt*512 + (s*32 + v*8)*2) ^ ((pt & 31) << 4);
      *(u32x4*)((char*)X + byt) = prod;
    }
  } else {
    #pragma unroll
    for (int i=0; i<3; i++){
      int id = tid + i*256;
      int row = id / 12, sub = id - row*12;
      short8 v = *(const short8*)(feats + (size_t)(n0+row)*96 + sub*8);
      int byt = (row*512 + sub*16) ^ ((row & 31) << 4);
      *(short8*)((char*)X + byt) = v;
    }
  }
  __syncthreads();

  floatx4 acc[4][4];
  u32 pk[4][4][2];

  // ---- L0: K=96
  init_acc(l0_b, wb, lg, acc);
  mm_tile<3>(X, l0T, ftbase, lane, acc);
  __syncthreads();
  #pragma unroll
  for (int rf=0; rf<4; rf++){
    int fby = (wb + rf*16 + lg*4)*2;
    #pragma unroll
    for (int cf=0; cf<4; cf++){
      int pt = cf*16 + lr;
      u32 p0 = pkrtz(acc[rf][cf][0], acc[rf][cf][1]);
      u32 p1 = pkrtz(acc[rf][cf][2], acc[rf][cf][3]);
      pk[rf][cf][0] = p0; pk[rf][cf][1] = p1;
      int byt = (pt*512 + fby) ^ ((pt & 31) << 4);
      *(u32x2*)((char*)X + byt) = (u32x2){p0, p1};
    }
  }
  __syncthreads();

  // ---- 3 ResBlocks
  for (int rb=0; rb<3; rb++){
    const u16* W0 = resT + (size_t)(rb*3+0)*65536;
    const u16* W1 = resT + (size_t)(rb*3+1)*65536;
    const u16* W2 = resT + (size_t)(rb*3+2)*65536;
    const float* b0 = res_b + (rb*3+0)*256;
    const float* b1 = res_b + (rb*3+1)*256;
    const float* b2 = res_b + (rb*3+2)*256;

    init_acc(b0, wb, lg, acc);
    mm_tile<8>(X, W0, ftbase, lane, acc);
    __syncthreads();
    #pragma unroll
    for (int rf=0; rf<4; rf++){
      int fby = (wb + rf*16 + lg*4)*2;
      #pragma unroll
      for (int cf=0; cf<4; cf++){
        int pt = cf*16 + lr;
        u32 p0 = pkadd(pk[rf][cf][0], pkmax0(pkrtz(acc[rf][cf][0], acc[rf][cf][1])));
        u32 p1 = pkadd(pk[rf][cf][1], pkmax0(pkrtz(acc[rf][cf][2], acc[rf][cf][3])));
        pk[rf][cf][0] = p0; pk[rf][cf][1] = p1;   // pk now holds res
        int byt = (pt*512 + fby) ^ ((pt & 31) << 4);
        *(u32x2*)((char*)X + byt) = (u32x2){p0, p1};
      }
    }
    __syncthreads();

    init_acc(b1, wb, lg, acc);
    mm_tile<8>(X, W1, ftbase, lane, acc);
    __syncthreads();
    #pragma unroll
    for (int rf=0; rf<4; rf++){
      int fby = (wb + rf*16 + lg*4)*2;
      #pragma unroll
      for (int cf=0; cf<4; cf++){
        int pt = cf*16 + lr;
        u32 p0 = pkmax0(pkrtz(acc[rf][cf][0], acc[rf][cf][1]));
        u32 p1 = pkmax0(pkrtz(acc[rf][cf][2], acc[rf][cf][3]));
        int byt = (pt*512 + fby) ^ ((pt & 31) << 4);
        *(u32x2*)((char*)X + byt) = (u32x2){p0, p1};
      }
    }
    __syncthreads();

    init_acc(b2, wb, lg, acc);
    mm_tile<8>(X, W2, ftbase, lane, acc);
    __syncthreads();
    #pragma unroll
    for (int rf=0; rf<4; rf++){
      int fby = (wb + rf*16 + lg*4)*2;
      #pragma unroll
      for (int cf=0; cf<4; cf++){
        int pt = cf*16 + lr;
        u32 p0 = pkadd(pkmax0(pkrtz(acc[rf][cf][0], acc[rf][cf][1])), pk[rf][cf][0]);
        u32 p1 = pkadd(pkmax0(pkrtz(acc[rf][cf][2], acc[rf][cf][3])), pk[rf][cf][1]);
        pk[rf][cf][0] = p0; pk[rf][cf][1] = p1;   // pk now holds new x
        int byt = (pt*512 + fby) ^ ((pt & 31) << 4);
        *(u32x2*)((char*)X + byt) = (u32x2){p0, p1};
      }
    }
    __syncthreads();
  }

  // ---- final: 256 -> 16, sigmoid
  floatx4 accf;
  {
    float4 bo = *(const float4*)(l1_b + lg*4);
    accf = (floatx4){bo.x, bo.y, bo.z, bo.w};
  }
  #pragma unroll 1
  for (int ks=0; ks<8; ks++){
    int pt = wave*16 + lr;
    int byt = (pt*512 + (ks*32 + lg*8)*2) ^ ((pt&31)<<4);
    half8 x = *(const half8*)((const char*)X + byt);
    half8 w = *(const half8*)(l1T + ((size_t)ks*64 + lane)*8);
    accf = __builtin_amdgcn_mfma_f32_16x16x32_f16(w, x, accf, 0, 0, 0);
  }
  {
    int n_out = n0 + wave*16 + lr;
    float4 o;
    o.x = 1.0f / (1.0f + __expf(-accf[0]));
    o.y = 1.0f / (1.0f + __expf(-accf[1]));
    o.z = 1.0f / (1.0f + __expf(-accf[2]));
    o.w = 1.0f / (1.0f + __expf(-accf[3]));
    *(float4*)(out + (size_t)n_out*16 + lg*4) = o;
  }
}

// ---------------- host ----------------
extern "C" void kernel_launch(void* const* d_in, const int* in_sizes, int n_in,
                              void* d_out, int out_size, void* d_ws, size_t ws_size,
                              hipStream_t stream)
{
  const float* pts  = (const float*)d_in[0];
  const float* aabb = (const float*)d_in[1];
  const float* l0_w = (const float*)d_in[11];
  const float* res_w= (const float*)d_in[13];
  const float* l1_w = (const float*)d_in[15];
  const float* l0_b = (const float*)d_in[12];
  const float* res_b= (const float*)d_in[14];
  const float* l1_b = (const float*)d_in[16];
  const int N = in_sizes[0] / 3;

  char* ws = (char*)d_ws;
  const size_t woff_l0  = 0;                          // 256*96*2
  const size_t woff_res = 49152;                      // 9*65536*2
  const size_t woff_l1  = woff_res + 9*65536*2;       // 16*256*2
  const size_t foff     = woff_l1 + 8192;             // fallback feats: N*96*2
  const size_t poff     = foff + (size_t)N*96*2;      // f16 planes

  static const int HWs[3] = {128*128, 256*256, 512*512};
  size_t pel[9]; size_t tot = 0;
  for (int s=0;s<3;s++) for (int p=0;p<3;p++){ pel[s*3+p] = tot; tot += (size_t)HWs[s]*32; }

  const bool tr_mode = (ws_size >= poff + tot*2);

  PlanePtrs pp;
  if (tr_mode){
    u16* pbase = (u16*)(ws + poff);
    PrepArgs pa;
    int b0 = 0;
    for (int i=0;i<9;i++){
      int s = i/3;
      pa.src[i] = (const float*)d_in[2+i];
      pa.dst[i] = pbase + pel[i];
      pa.blk0[i] = b0;
      pa.HW[i] = HWs[s];
      b0 += HWs[s]/256;
      pp.p[i] = pbase + pel[i];
    }
    pa.blk0[9] = b0;
    pa.ptrans_blocks = b0;
    pa.l0_w = l0_w; pa.res_w = res_w; pa.l1_w = l1_w;
    pa.l0T = (u16*)(ws+woff_l0); pa.resT = (u16*)(ws+woff_res); pa.l1T = (u16*)(ws+woff_l1);
    const int wconv_blocks = (24576+589824+4096+255)/256;
    prep_all_kernel<<<b0 + wconv_blocks, 256, 0, stream>>>(pa);

    mlp_kernel<1><<<N/64, 256, 0, stream>>>(pts, aabb, pp, (const u16*)nullptr,
        (const u16*)(ws+woff_l0), (const u16*)(ws+woff_res), (const u16*)(ws+woff_l1),
        l0_b, res_b, l1_b, (float*)d_out);
  } else {
    PrepArgs pa;
    for (int i=0;i<9;i++){ pa.src[i] = nullptr; pa.dst[i] = nullptr; pa.blk0[i] = 0; pa.HW[i] = HWs[i/3]; pp.p[i] = d_in[2+i]; }
    pa.blk0[9] = 0;
    pa.ptrans_blocks = 0;
    pa.l0_w = l0_w; pa.res_w = res_w; pa.l1_w = l1_w;
    pa.l0T = (u16*)(ws+woff_l0); pa.resT = (u16*)(ws+woff_res); pa.l1T = (u16*)(ws+woff_l1);
    const int wconv_blocks = (24576+589824+4096+255)/256;
    prep_all_kernel<<<wconv_blocks, 256, 0, stream>>>(pa);

    interp_fb_kernel<<<(N+255)/256, 256, 0, stream>>>(pts, aabb, pp, (u16*)(ws+foff), N);
    mlp_kernel<0><<<N/64, 256, 0, stream>>>(pts, aabb, pp, (const u16*)(ws+foff),
        (const u16*)(ws+woff_l0), (const u16*)(ws+woff_res), (const u16*)(ws+woff_l1),
        l0_b, res_b, l1_b, (float*)d_out);
  }
}